// Round 7
// baseline (129.171 us; speedup 1.0000x reference)
//
#include <hip/hip_runtime.h>
#include <math.h>

// KTVLoss: inputs out_l, out_r, input_i : (8,3,512,512) fp32. Output: 1 fp32 scalar.
//
// Sx = 10x10 box sum of |dI/dh| (502x503), Sy = box sum of |dI/dw| (503x502).
// Reference pairs them by FLAT index: Sx(i,j) with Sy(i,i+j) if i+j<502 else
// Sy(i+1,i+j-502). ratio = (SxL+SyL+SxR+SyR)/(SxI+SyI+1e-4), mean over 24*502*503.
// grad part (fp32): mean|GxL+GxR-GxI| + mean|GyL+GyR-GyI| over 24*511*512 each.
// norm part carries 1e-4 weight -> packed f16 (abs err ~1e-5; validated R4-R9).
//
// R17: R16 was time-neutral but dropped VGPR 124->52 and exposed the real
// cap: 504 blocks on 256 CUs = 1.97 blocks/CU -- the ~46% residual stall is
// both co-resident blocks barrier-waiting simultaneously. This round buys a
// THIRD independent block per CU:
//  - RB 24->16: 32 bands x 24 imgs = 768 blocks = exactly 3/CU.
//  - 1-row supersteps (2-row pairing was only -4.5% and doubles LDS):
//    rows ring depth 4 (consume s / land s+1 / issue s+2, counted vmcnt(3)),
//    awin depth 2 (write s, read s+1), syring depth 4 (write s-10, read
//    s-12/s-11; 1-barrier write-vs-read gap verified). LDS 41.1 KB -> 3x fits
//    160 KB.
//  - __launch_bounds__(512,6): 6 waves/SIMD = 3 blocks/CU, VGPR cap 85.
// Schedule invariants kept from R12-R16: all LDS reads at superstep top,
// stage mid, LDS writes aged before the lgkm(0)+barrier drain, snap 2-deep
// delay (ratio lag -12), clamp-dup tail staging for uniform vmcnt cadence.
//
// VGPR cap law: cap = 512/min_waves_per_EU; (512,6) -> 85. Watch for spill
// (symptom: WRITE_SIZE >> 24 KB).

namespace {

constexpr int H = 512, W = 512;
constexpr int CX = W - 10 + 1;   // 503 Sx cols (Sy has 503 rows)
constexpr int CY = W - 10;       // 502 Sy cols
constexpr int RB = 16;           // Sx rows per band
constexpr int NBANDS = (CY + RB - 1) / RB;   // 32
constexpr int NIMG = 24;
constexpr int NBLOCKS = NIMG * NBANDS;       // 768 = 3 per CU

constexpr int SMAX = RB + 9;     // last scan row offset (25)
constexpr int NSTEP = RB + 12;   // supersteps: ratios end at s = RB+11 (27)

constexpr int ROWSZ = 3 * 513;   // floats per row-slot (L,R,I channels + pad col)

typedef __fp16 h2 __attribute__((ext_vector_type(2)));

__device__ __forceinline__ int h2i(h2 v) { int r; __builtin_memcpy(&r, &v, 4); return r; }
__device__ __forceinline__ h2 i2h(int v) { h2 r; __builtin_memcpy(&r, &v, 4); return r; }

template <int C, int RM>
__device__ __forceinline__ int dppmov(int v) {
  return __builtin_amdgcn_update_dpp(0, v, C, RM, 0xf, true);
}
// full 64-lane inclusive prefix sum of a f16x2 pack (pure VALU)
__device__ __forceinline__ h2 scan64(h2 v) {
  v += i2h(dppmov<0x111, 0xf>(h2i(v)));  // row_shr:1
  v += i2h(dppmov<0x112, 0xf>(h2i(v)));  // row_shr:2
  v += i2h(dppmov<0x114, 0xf>(h2i(v)));  // row_shr:4
  v += i2h(dppmov<0x118, 0xf>(h2i(v)));  // row_shr:8
  v += i2h(dppmov<0x142, 0xa>(h2i(v)));  // row_bcast15 -> rows 1,3
  v += i2h(dppmov<0x143, 0xc>(h2i(v)));  // row_bcast31 -> rows 2,3
  return v;
}

// async global->LDS, 4 bytes/lane, dest = wave-uniform base + lane*4
__device__ __forceinline__ void gload(const float* g, float* l) {
  __builtin_amdgcn_global_load_lds((const __attribute__((address_space(1))) void*)g,
                                   (__attribute__((address_space(3))) void*)l, 4, 0, 0);
}

// barrier with COUNTED vmcnt(3): lgkmcnt(0) for LDS visibility; the current
// superstep's 3 staging loads stay in flight across the barrier (never 0).
// Loads of step s are retired by the barrier of step s+1 (which has issued 3
// newer loads), before their row is read at step s+2. encoding: vmcnt[3:0]=3,
// exp[6:4]=7(max), lgkm[11:8]=0.
__device__ __forceinline__ void kbarrier_vm() {
  __builtin_amdgcn_sched_barrier(0);
  __builtin_amdgcn_s_waitcnt(0x0073);
  __builtin_amdgcn_s_barrier();
  __builtin_amdgcn_sched_barrier(0);
}

}  // namespace

__global__ __launch_bounds__(512, 6) void ktv_main(const float* __restrict__ L,
                                                   const float* __restrict__ R,
                                                   const float* __restrict__ I,
                                                   double* __restrict__ partial) {
  const int blk = blockIdx.x;
  const int img = blk / NBANDS;
  const int band = blk % NBANDS;
  const int i0 = band * RB;
  const int j = threadIdx.x;  // column
  const int lane = j & 63;
  const int wv = j >> 6;
  const int wtop = (wv + 1) << 6;               // awin slot holding own wave's total
  const bool patch = (lane >= 55) && (wv < 7);  // window crosses into next wave

  const bool lastb = (band == NBANDS - 1);
  const int gyEnd = lastb ? H : (i0 + RB);        // Gy rows owned: [i0, gyEnd)
  const int gxEnd = lastb ? (H - 1) : (i0 + RB);  // Gx rows owned: [i0, gxEnd)
  const int sxEnd = lastb ? CY : (i0 + RB);       // Sx rows owned: [i0, sxEnd)

  const size_t base = (size_t)img * (H * W);
  const float* pL = L + base;
  const float* pR = R + base;
  const float* pI = I + base;

  __shared__ float rows[4 * ROWSZ];   // staged input rows, depth-4 ring (+pad col)
  __shared__ int syring[4 * CY];      // completed Sy rows (f16x2 n,d), depth-4 ring
  __shared__ int2 awin[2 * 522];      // prefix packs [parity][col]
                                      // col k = prefix through col k-1; [64w]=T_{w-1}
  __shared__ float redN[8], redG[8];

  // hist as a 10-deep shift-register queue (registers; constant-index shift)
  h2 hqY[10], hqX[10];
#pragma unroll
  for (int t = 0; t < 10; ++t) { hqY[t] = (h2)(__fp16)0; hqX[t] = (h2)(__fp16)0; }
  h2 runY = (h2)(__fp16)0, runX = (h2)(__fp16)0;
  h2 snap1 = (h2)(__fp16)0, snap2 = snap1;
  float accN = 0.f, accG = 0.f;
  float prevL = 0.f, prevR = 0.f, prevI = 0.f;

  // prologue: stage rows 0,1 (6 loads; i0+1 <= 497, no clamp); zero pad col
#pragma unroll
  for (int q = 0; q < 2; ++q) {
    const int g = (i0 + q) * W + j;
    gload(pL + g, &rows[q * ROWSZ + wv * 64]);
    gload(pR + g, &rows[q * ROWSZ + 513 + wv * 64]);
    gload(pI + g, &rows[q * ROWSZ + 1026 + wv * 64]);
  }
  if (j < 12) rows[(j / 3) * ROWSZ + (j % 3) * 513 + 512] = 0.f;
  __builtin_amdgcn_sched_barrier(0);
  __builtin_amdgcn_s_waitcnt(0x0073);  // vmcnt(3): row 0 landed; lgkm(0): pad
  __builtin_amdgcn_s_barrier();
  __builtin_amdgcn_sched_barrier(0);

  // NSTEP 1-row supersteps: scan s=0..25, patch (row s-1) s=1..26, ratio s=12..27
#pragma clang loop unroll(disable)
  for (int s = 0; s < NSTEP; ++s) {
    const bool doScan = (s <= SMAX);
    const bool doPatch = (s >= 1) && (s <= SMAX + 1);
    const bool doRatio = (s >= 12);
    const int aWr = (s & 1) * 522;   // awin write parity base
    const int aRd = aWr ^ 522;       // awin read parity base (written at s-1)

    // ---- top: syring read for ratio Sx row s-12 ----
    int syrd = 0;
    bool uok = false;
    if (doRatio) {
      const int u = i0 + s - 12;
      if (u < sxEnd && j < CX) {
        int jy = u + j, rw = u;
        if (jy >= CY) { jy -= CY; ++rw; }
        syrd = syring[(rw & 3) * CY + jy];
        uok = true;
      }
    }

    // ---- top: awin prefix reads for patch row s-1 (written at s-1) ----
    int2 w0 = make_int2(0, 0), w10 = w0, wT = w0;
    if (doPatch) {
      w0 = awin[aRd + j];
      w10 = awin[aRd + j + 10];
      wT = awin[aRd + wtop];
    }

    // ---- top: row s values, cols j and j+1 (ds_read2_b32 pairs) ----
    float xVL = 0.f, xVR = 0.f, xVI = 0.f, xNL = 0.f, xNR = 0.f, xNI = 0.f;
    if (doScan) {
      const int ro = (s & 3) * ROWSZ;
      xVL = rows[ro + j];        xNL = rows[ro + j + 1];
      xVR = rows[ro + 513 + j];  xNR = rows[ro + 513 + j + 1];
      xVI = rows[ro + 1026 + j]; xNI = rows[ro + 1026 + j + 1];
    }

    // ---- stage row s+2 (clamp-dup at tail keeps the vmcnt cadence) ----
    {
      int srow = s + 2; if (srow > SMAX) srow = SMAX;  // dup rewrites same bytes
      const int d = (srow & 3) * ROWSZ;
      int grow = i0 + srow; if (grow > H - 1) grow = H - 1;  // lastb clamp
      const int g = grow * W + j;
      gload(pL + g, &rows[d + wv * 64]);
      gload(pR + g, &rows[d + 513 + wv * 64]);
      gload(pI + g, &rows[d + 1026 + wv * 64]);
    }

    // ---- scan row s: gradients, packs, DPP scan -> awin write (aged) ----
    if (doScan) {
      const int r = i0 + s;
      const float gyl = xNL - xVL, gyr = xNR - xVR, gyi = xNI - xVI;
      const float gxl = xVL - prevL, gxr = xVR - prevR, gxi = xVI - prevI;
      prevL = xVL; prevR = xVR; prevI = xVI;
      if (r < gyEnd && j < W - 1) accG += fabsf(gyl + gyr - gyi);
      if (s > 0 && (r - 1) < gxEnd) accG += fabsf(gxl + gxr - gxi);
      float yn = fabsf(gyl) + fabsf(gyr), yd = fabsf(gyi);
      float xn = fabsf(gxl) + fabsf(gxr), xd = fabsf(gxi);
      if (j == W - 1) { yn = 0.f; yd = 0.f; }
      if (r >= H) { yn = 0.f; yd = 0.f; xn = 0.f; xd = 0.f; }
      const h2 Y = __builtin_amdgcn_cvt_pkrtz(yn, yd);
      h2 X = (h2)(__fp16)0;
      if (s != 0) X = __builtin_amdgcn_cvt_pkrtz(xn, xd);
      const h2 AY = scan64(Y), AX = scan64(X);
      awin[aWr + j + 1] = make_int2(h2i(AY), h2i(AX));
    }

    // ---- ratio finish: snap2 = Sx row s-12 (set at patch of step s-2) ----
    if (uok) {
      const h2 sy = i2h(syrd);
      const float num = (float)snap2.x + (float)sy.x;
      const float den = (float)snap2.y + (float)sy.y + 1e-4f;
      accN += num * __builtin_amdgcn_rcpf(den);
    }
    snap2 = snap1;  // 2-deep delay line

    // ---- patch row s-1: window combine, vertical ring, syring write ----
    if (doPatch) {
      h2 hh = i2h(w10.x), hx = i2h(w10.y);
      if (lane != 0) { hh -= i2h(w0.x); hx -= i2h(w0.y); }
      if (patch) { hh += i2h(wT.x); hx += i2h(wT.y); }
      runY += hh - hqY[0]; runX += hx - hqX[0];
      snap1 = runX;  // Sx row s-10
      {
        const int iY = i0 + s - 10;  // Sy row s-10 complete
        if (s >= 10 && iY <= sxEnd && j < CY) syring[(iY & 3) * CY + j] = h2i(runY);
      }
      // queue: shift by 1, insert the new window value
#pragma unroll
      for (int k = 0; k < 9; ++k) { hqY[k] = hqY[k + 1]; hqX[k] = hqX[k + 1]; }
      hqY[9] = hh; hqX[9] = hx;
    }

    kbarrier_vm();
  }

  // block reduction (2 channels)
#pragma unroll
  for (int o2 = 32; o2 > 0; o2 >>= 1) {
    accN += __shfl_down(accN, o2);
    accG += __shfl_down(accG, o2);
  }
  if (lane == 0) { redN[wv] = accN; redG[wv] = accG; }
  __syncthreads();
  if (j == 0) {
    float n = 0.f, g = 0.f;
#pragma unroll
    for (int w2 = 0; w2 < 8; ++w2) { n += redN[w2]; g += redG[w2]; }
    double* p = partial + (size_t)blk * 2;
    p[0] = (double)n; p[1] = (double)g;
  }
}

__global__ __launch_bounds__(64) void ktv_reduce(const double* __restrict__ partial,
                                                 float* __restrict__ out) {
  double n = 0.0, g = 0.0;
  for (int i = threadIdx.x; i < NBLOCKS; i += 64) {
    const double* p = partial + (size_t)i * 2;
    n += p[0]; g += p[1];
  }
#pragma unroll
  for (int o2 = 32; o2 > 0; o2 >>= 1) {
    n += __shfl_down(n, o2);
    g += __shfl_down(g, o2);
  }
  if (threadIdx.x == 0) {
    const double norm_loss = n / 6060144.0;  // 24*502*503
    const double grad_loss = g / 6279168.0;  // 24*511*512 (gx and gy share denom)
    out[0] = (float)(1e-4 * norm_loss + grad_loss);
  }
}

extern "C" void kernel_launch(void* const* d_in, const int* in_sizes, int n_in,
                              void* d_out, int out_size, void* d_ws, size_t ws_size,
                              hipStream_t stream) {
  (void)in_sizes; (void)n_in; (void)out_size; (void)ws_size;
  const float* L = (const float*)d_in[0];
  const float* R = (const float*)d_in[1];
  const float* I = (const float*)d_in[2];
  double* partial = (double*)d_ws;  // NBLOCKS*2 doubles = 12288 B
  float* out = (float*)d_out;

  hipLaunchKernelGGL(ktv_main, dim3(NBLOCKS), dim3(512), 0, stream, L, R, I, partial);
  hipLaunchKernelGGL(ktv_reduce, dim3(1), dim3(64), 0, stream, partial, out);
}

// Round 8
// 123.364 us; speedup vs baseline: 1.0471x; 1.0471x over previous
//
#include <hip/hip_runtime.h>
#include <math.h>

// KTVLoss: inputs out_l, out_r, input_i : (8,3,512,512) fp32. Output: 1 fp32 scalar.
//
// Sx = 10x10 box sum of |dI/dh| (502x503), Sy = box sum of |dI/dw| (503x502).
// Reference pairs them by FLAT index: Sx(i,j) with Sy(i,i+j) if i+j<502 else
// Sy(i+1,i+j-502). ratio = (SxL+SyL+SxR+SyR)/(SxI+SyI+1e-4), mean over 24*502*503.
// grad part (fp32): mean|GxL+GxR-GxI| + mean|GyL+GyR-GyI| over 24*511*512 each.
// norm part carries 1e-4 weight -> packed f16 (abs err ~1e-5; validated R4-R9).
//
// R18: R17 reached 3 blocks/CU (occupancy 43%, VALUBusy 70%, VGPR 40) --
// now VALU-ISSUE-bound: ~225 instr/step/wave x 2cyc x 6 waves/SIMD ~= 2700
// of the 3860-cyc superstep. Floor at current instr count ~31us. The fat is
// codegen: 10-deep hist shift (18 movs/row), per-step addressing re-derive,
// per-step guard eval -- all artifacts of the 1-step rolled body. This round:
// single change, #pragma clang loop unroll_count(4) (28 = 7x4). Register
// allocation is global, so the x4 copies coalesce the hist shifts into a net
// shift-by-4 at the back edge (12 movs/4 rows vs 72), strength-reduce the
// induction addressing, and fold uniform guards. R16 proved text size is
// free; sched_barrier(0) pins order but not register coalescing. LDS /
// occupancy / schedule invariants identical to R17.
//
// VGPR cap law: cap = 512/min_waves_per_EU; (512,6) -> 85. Watch for spill
// (symptom: WRITE_SIZE >> 24 KB).

namespace {

constexpr int H = 512, W = 512;
constexpr int CX = W - 10 + 1;   // 503 Sx cols (Sy has 503 rows)
constexpr int CY = W - 10;       // 502 Sy cols
constexpr int RB = 16;           // Sx rows per band
constexpr int NBANDS = (CY + RB - 1) / RB;   // 32
constexpr int NIMG = 24;
constexpr int NBLOCKS = NIMG * NBANDS;       // 768 = 3 per CU

constexpr int SMAX = RB + 9;     // last scan row offset (25)
constexpr int NSTEP = RB + 12;   // supersteps: ratios end at s = RB+11 (27); 28 = 7*4

constexpr int ROWSZ = 3 * 513;   // floats per row-slot (L,R,I channels + pad col)

typedef __fp16 h2 __attribute__((ext_vector_type(2)));

__device__ __forceinline__ int h2i(h2 v) { int r; __builtin_memcpy(&r, &v, 4); return r; }
__device__ __forceinline__ h2 i2h(int v) { h2 r; __builtin_memcpy(&r, &v, 4); return r; }

template <int C, int RM>
__device__ __forceinline__ int dppmov(int v) {
  return __builtin_amdgcn_update_dpp(0, v, C, RM, 0xf, true);
}
// full 64-lane inclusive prefix sum of a f16x2 pack (pure VALU)
__device__ __forceinline__ h2 scan64(h2 v) {
  v += i2h(dppmov<0x111, 0xf>(h2i(v)));  // row_shr:1
  v += i2h(dppmov<0x112, 0xf>(h2i(v)));  // row_shr:2
  v += i2h(dppmov<0x114, 0xf>(h2i(v)));  // row_shr:4
  v += i2h(dppmov<0x118, 0xf>(h2i(v)));  // row_shr:8
  v += i2h(dppmov<0x142, 0xa>(h2i(v)));  // row_bcast15 -> rows 1,3
  v += i2h(dppmov<0x143, 0xc>(h2i(v)));  // row_bcast31 -> rows 2,3
  return v;
}

// async global->LDS, 4 bytes/lane, dest = wave-uniform base + lane*4
__device__ __forceinline__ void gload(const float* g, float* l) {
  __builtin_amdgcn_global_load_lds((const __attribute__((address_space(1))) void*)g,
                                   (__attribute__((address_space(3))) void*)l, 4, 0, 0);
}

// barrier with COUNTED vmcnt(3): lgkmcnt(0) for LDS visibility; the current
// superstep's 3 staging loads stay in flight across the barrier (never 0).
// Loads of step s are retired by the barrier of step s+1 (which has issued 3
// newer loads), before their row is read at step s+2. encoding: vmcnt[3:0]=3,
// exp[6:4]=7(max), lgkm[11:8]=0.
__device__ __forceinline__ void kbarrier_vm() {
  __builtin_amdgcn_sched_barrier(0);
  __builtin_amdgcn_s_waitcnt(0x0073);
  __builtin_amdgcn_s_barrier();
  __builtin_amdgcn_sched_barrier(0);
}

}  // namespace

__global__ __launch_bounds__(512, 6) void ktv_main(const float* __restrict__ L,
                                                   const float* __restrict__ R,
                                                   const float* __restrict__ I,
                                                   double* __restrict__ partial) {
  const int blk = blockIdx.x;
  const int img = blk / NBANDS;
  const int band = blk % NBANDS;
  const int i0 = band * RB;
  const int j = threadIdx.x;  // column
  const int lane = j & 63;
  const int wv = j >> 6;
  const int wtop = (wv + 1) << 6;               // awin slot holding own wave's total
  const bool patch = (lane >= 55) && (wv < 7);  // window crosses into next wave

  const bool lastb = (band == NBANDS - 1);
  const int gyEnd = lastb ? H : (i0 + RB);        // Gy rows owned: [i0, gyEnd)
  const int gxEnd = lastb ? (H - 1) : (i0 + RB);  // Gx rows owned: [i0, gxEnd)
  const int sxEnd = lastb ? CY : (i0 + RB);       // Sx rows owned: [i0, sxEnd)

  const size_t base = (size_t)img * (H * W);
  const float* pL = L + base;
  const float* pR = R + base;
  const float* pI = I + base;

  __shared__ float rows[4 * ROWSZ];   // staged input rows, depth-4 ring (+pad col)
  __shared__ int syring[4 * CY];      // completed Sy rows (f16x2 n,d), depth-4 ring
  __shared__ int2 awin[2 * 522];      // prefix packs [parity][col]
                                      // col k = prefix through col k-1; [64w]=T_{w-1}
  __shared__ float redN[8], redG[8];

  // hist as a 10-deep shift-register queue (registers; constant-index shift;
  // unroll_count(4) coalesces the 4 per-copy shifts into one net shift-by-4)
  h2 hqY[10], hqX[10];
#pragma unroll
  for (int t = 0; t < 10; ++t) { hqY[t] = (h2)(__fp16)0; hqX[t] = (h2)(__fp16)0; }
  h2 runY = (h2)(__fp16)0, runX = (h2)(__fp16)0;
  h2 snap1 = (h2)(__fp16)0, snap2 = snap1;
  float accN = 0.f, accG = 0.f;
  float prevL = 0.f, prevR = 0.f, prevI = 0.f;

  // prologue: stage rows 0,1 (6 loads; i0+1 <= 497, no clamp); zero pad col
#pragma unroll
  for (int q = 0; q < 2; ++q) {
    const int g = (i0 + q) * W + j;
    gload(pL + g, &rows[q * ROWSZ + wv * 64]);
    gload(pR + g, &rows[q * ROWSZ + 513 + wv * 64]);
    gload(pI + g, &rows[q * ROWSZ + 1026 + wv * 64]);
  }
  if (j < 12) rows[(j / 3) * ROWSZ + (j % 3) * 513 + 512] = 0.f;
  __builtin_amdgcn_sched_barrier(0);
  __builtin_amdgcn_s_waitcnt(0x0073);  // vmcnt(3): row 0 landed; lgkm(0): pad
  __builtin_amdgcn_s_barrier();
  __builtin_amdgcn_sched_barrier(0);

  // NSTEP 1-row supersteps: scan s=0..25, patch (row s-1) s=1..26, ratio s=12..27
#pragma clang loop unroll_count(4)
  for (int s = 0; s < NSTEP; ++s) {
    const bool doScan = (s <= SMAX);
    const bool doPatch = (s >= 1) && (s <= SMAX + 1);
    const bool doRatio = (s >= 12);
    const int aWr = (s & 1) * 522;   // awin write parity base
    const int aRd = aWr ^ 522;       // awin read parity base (written at s-1)

    // ---- top: syring read for ratio Sx row s-12 ----
    int syrd = 0;
    bool uok = false;
    if (doRatio) {
      const int u = i0 + s - 12;
      if (u < sxEnd && j < CX) {
        int jy = u + j, rw = u;
        if (jy >= CY) { jy -= CY; ++rw; }
        syrd = syring[(rw & 3) * CY + jy];
        uok = true;
      }
    }

    // ---- top: awin prefix reads for patch row s-1 (written at s-1) ----
    int2 w0 = make_int2(0, 0), w10 = w0, wT = w0;
    if (doPatch) {
      w0 = awin[aRd + j];
      w10 = awin[aRd + j + 10];
      wT = awin[aRd + wtop];
    }

    // ---- top: row s values, cols j and j+1 (ds_read2_b32 pairs) ----
    float xVL = 0.f, xVR = 0.f, xVI = 0.f, xNL = 0.f, xNR = 0.f, xNI = 0.f;
    if (doScan) {
      const int ro = (s & 3) * ROWSZ;
      xVL = rows[ro + j];        xNL = rows[ro + j + 1];
      xVR = rows[ro + 513 + j];  xNR = rows[ro + 513 + j + 1];
      xVI = rows[ro + 1026 + j]; xNI = rows[ro + 1026 + j + 1];
    }

    // ---- stage row s+2 (clamp-dup at tail keeps the vmcnt cadence) ----
    {
      int srow = s + 2; if (srow > SMAX) srow = SMAX;  // dup rewrites same bytes
      const int d = (srow & 3) * ROWSZ;
      int grow = i0 + srow; if (grow > H - 1) grow = H - 1;  // lastb clamp
      const int g = grow * W + j;
      gload(pL + g, &rows[d + wv * 64]);
      gload(pR + g, &rows[d + 513 + wv * 64]);
      gload(pI + g, &rows[d + 1026 + wv * 64]);
    }

    // ---- scan row s: gradients, packs, DPP scan -> awin write (aged) ----
    if (doScan) {
      const int r = i0 + s;
      const float gyl = xNL - xVL, gyr = xNR - xVR, gyi = xNI - xVI;
      const float gxl = xVL - prevL, gxr = xVR - prevR, gxi = xVI - prevI;
      prevL = xVL; prevR = xVR; prevI = xVI;
      if (r < gyEnd && j < W - 1) accG += fabsf(gyl + gyr - gyi);
      if (s > 0 && (r - 1) < gxEnd) accG += fabsf(gxl + gxr - gxi);
      float yn = fabsf(gyl) + fabsf(gyr), yd = fabsf(gyi);
      float xn = fabsf(gxl) + fabsf(gxr), xd = fabsf(gxi);
      if (j == W - 1) { yn = 0.f; yd = 0.f; }
      if (r >= H) { yn = 0.f; yd = 0.f; xn = 0.f; xd = 0.f; }
      const h2 Y = __builtin_amdgcn_cvt_pkrtz(yn, yd);
      h2 X = (h2)(__fp16)0;
      if (s != 0) X = __builtin_amdgcn_cvt_pkrtz(xn, xd);
      const h2 AY = scan64(Y), AX = scan64(X);
      awin[aWr + j + 1] = make_int2(h2i(AY), h2i(AX));
    }

    // ---- ratio finish: snap2 = Sx row s-12 (set at patch of step s-2) ----
    if (uok) {
      const h2 sy = i2h(syrd);
      const float num = (float)snap2.x + (float)sy.x;
      const float den = (float)snap2.y + (float)sy.y + 1e-4f;
      accN += num * __builtin_amdgcn_rcpf(den);
    }
    snap2 = snap1;  // 2-deep delay line

    // ---- patch row s-1: window combine, vertical ring, syring write ----
    if (doPatch) {
      h2 hh = i2h(w10.x), hx = i2h(w10.y);
      if (lane != 0) { hh -= i2h(w0.x); hx -= i2h(w0.y); }
      if (patch) { hh += i2h(wT.x); hx += i2h(wT.y); }
      runY += hh - hqY[0]; runX += hx - hqX[0];
      snap1 = runX;  // Sx row s-10
      {
        const int iY = i0 + s - 10;  // Sy row s-10 complete
        if (s >= 10 && iY <= sxEnd && j < CY) syring[(iY & 3) * CY + j] = h2i(runY);
      }
      // queue: shift by 1, insert the new window value
#pragma unroll
      for (int k = 0; k < 9; ++k) { hqY[k] = hqY[k + 1]; hqX[k] = hqX[k + 1]; }
      hqY[9] = hh; hqX[9] = hx;
    }

    kbarrier_vm();
  }

  // block reduction (2 channels)
#pragma unroll
  for (int o2 = 32; o2 > 0; o2 >>= 1) {
    accN += __shfl_down(accN, o2);
    accG += __shfl_down(accG, o2);
  }
  if (lane == 0) { redN[wv] = accN; redG[wv] = accG; }
  __syncthreads();
  if (j == 0) {
    float n = 0.f, g = 0.f;
#pragma unroll
    for (int w2 = 0; w2 < 8; ++w2) { n += redN[w2]; g += redG[w2]; }
    double* p = partial + (size_t)blk * 2;
    p[0] = (double)n; p[1] = (double)g;
  }
}

__global__ __launch_bounds__(64) void ktv_reduce(const double* __restrict__ partial,
                                                 float* __restrict__ out) {
  double n = 0.0, g = 0.0;
  for (int i = threadIdx.x; i < NBLOCKS; i += 64) {
    const double* p = partial + (size_t)i * 2;
    n += p[0]; g += p[1];
  }
#pragma unroll
  for (int o2 = 32; o2 > 0; o2 >>= 1) {
    n += __shfl_down(n, o2);
    g += __shfl_down(g, o2);
  }
  if (threadIdx.x == 0) {
    const double norm_loss = n / 6060144.0;  // 24*502*503
    const double grad_loss = g / 6279168.0;  // 24*511*512 (gx and gy share denom)
    out[0] = (float)(1e-4 * norm_loss + grad_loss);
  }
}

extern "C" void kernel_launch(void* const* d_in, const int* in_sizes, int n_in,
                              void* d_out, int out_size, void* d_ws, size_t ws_size,
                              hipStream_t stream) {
  (void)in_sizes; (void)n_in; (void)out_size; (void)ws_size;
  const float* L = (const float*)d_in[0];
  const float* R = (const float*)d_in[1];
  const float* I = (const float*)d_in[2];
  double* partial = (double*)d_ws;  // NBLOCKS*2 doubles = 12288 B
  float* out = (float*)d_out;

  hipLaunchKernelGGL(ktv_main, dim3(NBLOCKS), dim3(512), 0, stream, L, R, I, partial);
  hipLaunchKernelGGL(ktv_reduce, dim3(1), dim3(64), 0, stream, partial, out);
}